// Round 23
// baseline (54.715 us; speedup 1.0000x reference)
//
#include <hip/hip_runtime.h>

// CRF loss: out[b] = logZ[b] - target[b].  B=256, S=2048, D=64.
// Round 23: r22 (52.8us, absmax 0.0) with ONE change: 3-deep prefetch
//   rotation (EA/EB/EC) -> 12 outstanding loads/wave instead of 8.
//   Scan triangulated as MLP-bound (occupancy x2: null; traffic +20%: null;
//   chain -30%: -3%). +17 VGPR only (r19's failure was 4x4 GROUP buffers).

#define B_   256
#define S_   2048
#define D_   64
#define CHK  128     // chunks per batch
#define CL   16      // accounted steps per chunk
#define WUP  4       // warmup steps

typedef float  f32x4 __attribute__((ext_vector_type(4)));
typedef short  v4s   __attribute__((ext_vector_type(4)));

#if __has_builtin(__builtin_amdgcn_mfma_f32_16x16x16bf16_1k)
static __device__ __forceinline__ f32x4 mfma16(v4s a, v4s b, f32x4 cc) {
    return __builtin_amdgcn_mfma_f32_16x16x16bf16_1k(a, b, cc, 0, 0, 0);
}
#else
static __device__ __forceinline__ f32x4 mfma16(v4s a, v4s b, f32x4 cc) {
    f32x4 d;
    asm("v_mfma_f32_16x16x16_bf16 %0, %1, %2, %3"
        : "=&v"(d) : "v"(a), "v"(b), "v"(cc));
    return d;
}
#endif

// f32 -> bf16 round-to-nearest-even (r15-verified; v_cvt_pk_bf16_f32 truncates)
static __device__ __forceinline__ unsigned bf16_rne(float x) {
    unsigned u = __float_as_uint(x);
    u += 0x7fffu + ((u >> 16) & 1u);
    return u >> 16;
}
static __device__ __forceinline__ float bf2f(short h) {
    return __uint_as_float(((unsigned)(unsigned short)h) << 16);
}
static __device__ __forceinline__ v4s pack4(float a, float b, float c2, float d) {
    union { uint2 u; v4s s; } uu;
    uu.u.x = bf16_rne(a) | (bf16_rne(b) << 16);
    uu.u.y = bf16_rne(c2) | (bf16_rne(d) << 16);
    return uu.s;
}

// ---------------- chunked MFMA forward scan ----------------
// wave u: batch group bg = u&15 (16 batches), chunk c = u>>4.
__global__ __launch_bounds__(64, 2) void mfma_chunk_scan(
    const float* __restrict__ y_pred, const float* __restrict__ mask,
    const float* __restrict__ trans, float* __restrict__ partials)
{
    const int u  = blockIdx.x;
    const int bg = u & 15;
    const int c  = u >> 4;
    const int l  = threadIdx.x;
    const int g  = l >> 4, cb = l & 15;   // g = row quad, cb = batch-in-group
    const int b0 = bg * 16;
    const float* yprowc = y_pred + (size_t)(b0 + cb) * S_ * D_;
    const float* mrowc  = mask   + (size_t)(b0 + cb) * S_;

    // A fragments (r5-verified layout): Av[m][kt] elem e =
    //   exp(trans[16kt+4g+e][16m+cb])
    v4s Av[4][4];
    #pragma unroll
    for (int m = 0; m < 4; ++m)
        #pragma unroll
        for (int kt = 0; kt < 4; ++kt) {
            float a0 = __expf(trans[(16*kt + 4*g + 0) * D_ + 16*m + cb]);
            float a1 = __expf(trans[(16*kt + 4*g + 1) * D_ + 16*m + cb]);
            float a2 = __expf(trans[(16*kt + 4*g + 2) * D_ + 16*m + cb]);
            float a3 = __expf(trans[(16*kt + 4*g + 3) * D_ + 16*m + cb]);
            Av[m][kt] = pack4(a0, a1, a2, a3);
        }

    // state B fragments: Bv[kt] elem e = p[state 16kt+4g+e][batch cb]
    v4s Bv[4];
    if (c == 0) {
        float m0 = mrowc[0];
        #pragma unroll
        for (int kt = 0; kt < 4; ++kt) {
            float p0 = __expf(yprowc[16*kt + 4*g + 0] * m0);
            float p1 = __expf(yprowc[16*kt + 4*g + 1] * m0);
            float p2 = __expf(yprowc[16*kt + 4*g + 2] * m0);
            float p3 = __expf(yprowc[16*kt + 4*g + 3] * m0);
            Bv[kt] = pack4(p0, p1, p2, p3);
        }
    } else {
        const short one = (short)0x3f80;          // bf16(1.0)
        v4s vone = {one, one, one, one};
        #pragma unroll
        for (int kt = 0; kt < 4; ++kt) Bv[kt] = vone;
    }

    int K = 0;                 // wave-uniform exact pow2 offset
    const f32x4 zf = {0.f, 0.f, 0.f, 0.f};

    auto mag = [&]() -> double {
        float s = 0.f;
        #pragma unroll
        for (int m = 0; m < 4; ++m)
            s += (bf2f(Bv[m][0]) + bf2f(Bv[m][1])) +
                 (bf2f(Bv[m][2]) + bf2f(Bv[m][3]));
        s += __shfl_xor(s, 16, 64);
        s += __shfl_xor(s, 32, 64);
        return (double)K * 0.6931471805599453 + (double)__logf(s);
    };

    const int t0    = (c == 0) ? 1 : CL * c - (WUP - 1);
    const int t_end = (CL * (c + 1) > S_ - 1) ? (S_ - 1) : CL * (c + 1);
    const int rec_t = CL * c;          // c>0: record m_start after this step
    double m_start = 0.0;

    // ee = exp(e) values (precomputed at load); cold masked path reloads raw e
    auto step = [&](int t, const float4 (&ee)[4], float cm) {
        // two independent 2-deep MFMA chains per m-tile, merged by one add
        f32x4 accA[4], accB[4];
        #pragma unroll
        for (int m = 0; m < 4; ++m) {
            accA[m] = mfma16(Av[m][0], Bv[0], zf);
            accB[m] = mfma16(Av[m][1], Bv[1], zf);
        }
        #pragma unroll
        for (int m = 0; m < 4; ++m) {
            accA[m] = mfma16(Av[m][2], Bv[2], accA[m]);
            accB[m] = mfma16(Av[m][3], Bv[3], accB[m]);
        }

        f32x4 pr[4];
        if (__builtin_expect(__all(cm == 1.0f), 1)) {
            #pragma unroll
            for (int m = 0; m < 4; ++m) {
                f32x4 acc = accA[m] + accB[m];
                pr[m][0] = acc[0] * ee[m].x;
                pr[m][1] = acc[1] * ee[m].y;
                pr[m][2] = acc[2] * ee[m].z;
                pr[m][3] = acc[3] * ee[m].w;
            }
        } else {
            // cold path: reload raw e (L2-hot), exact masked blend
            const float* ypr = yprowc + (size_t)t * D_ + 4 * g;
            #pragma unroll
            for (int m = 0; m < 4; ++m) {
                f32x4 acc = accA[m] + accB[m];
                #pragma unroll
                for (int e = 0; e < 4; ++e) {
                    float eraw = ypr[16 * m + e];
                    float sum  = acc[e];
                    float pold = bf2f(Bv[m][e]);
                    float pn;
                    if (cm == 1.0f) {
                        pn = sum * __expf(eraw);
                    } else {
                        float outn = __logf(sum) + eraw * cm;
                        float oldl = __logf(pold);
                        pn = __expf(cm * outn + (1.f - cm) * oldl);
                    }
                    pr[m][e] = pn;
                }
            }
        }

        if ((t & 3) == 0) {   // wave-uniform exact pow2 renorm (clamped)
            unsigned rep = __builtin_amdgcn_readfirstlane(__float_as_uint(pr[0][0]));
            int k = (int)((rep >> 23) & 0xffu) - 127;
            k = k < -110 ? -110 : (k > 110 ? 110 : k);
            float sc = __uint_as_float((unsigned)(127 - k) << 23);
            #pragma unroll
            for (int m = 0; m < 4; ++m) {
                pr[m][0] *= sc; pr[m][1] *= sc; pr[m][2] *= sc; pr[m][3] *= sc;
            }
            K += k;
        }

        #pragma unroll
        for (int m = 0; m < 4; ++m)
            Bv[m] = pack4(pr[m][0], pr[m][1], pr[m][2], pr[m][3]);
    };

    // 3-deep rotating prefetch; exp applied at load (off the step chain)
    float4 EA0, EA1, EA2, EA3, EB0, EB1, EB2, EB3, EC0, EC1, EC2, EC3;
    float  cmA, cmB, cmC;
    auto expf4 = [](float4 v) {
        float4 r; r.x = __expf(v.x); r.y = __expf(v.y);
        r.z = __expf(v.z); r.w = __expf(v.w); return r;
    };
    auto loadA = [&](int t) {
        int tt = t > t_end ? t_end : t;
        const float* base = yprowc + (size_t)tt * D_ + 4 * g;
        EA0 = expf4(*(const float4*)(base +  0));
        EA1 = expf4(*(const float4*)(base + 16));
        EA2 = expf4(*(const float4*)(base + 32));
        EA3 = expf4(*(const float4*)(base + 48));
        cmA = mrowc[tt];
    };
    auto loadB = [&](int t) {
        int tt = t > t_end ? t_end : t;
        const float* base = yprowc + (size_t)tt * D_ + 4 * g;
        EB0 = expf4(*(const float4*)(base +  0));
        EB1 = expf4(*(const float4*)(base + 16));
        EB2 = expf4(*(const float4*)(base + 32));
        EB3 = expf4(*(const float4*)(base + 48));
        cmB = mrowc[tt];
    };
    auto loadC = [&](int t) {
        int tt = t > t_end ? t_end : t;
        const float* base = yprowc + (size_t)tt * D_ + 4 * g;
        EC0 = expf4(*(const float4*)(base +  0));
        EC1 = expf4(*(const float4*)(base + 16));
        EC2 = expf4(*(const float4*)(base + 32));
        EC3 = expf4(*(const float4*)(base + 48));
        cmC = mrowc[tt];
    };

    loadA(t0); loadB(t0 + 1); loadC(t0 + 2);
    for (int t = t0; t <= t_end; t += 3) {
        {
            float4 ee[4] = {EA0, EA1, EA2, EA3}; float cm = cmA;
            loadA(t + 3);
            step(t, ee, cm);
            if (c > 0 && t == rec_t) m_start = mag();
        }
        if (t + 1 <= t_end) {
            float4 ee[4] = {EB0, EB1, EB2, EB3}; float cm = cmB;
            loadB(t + 4);
            step(t + 1, ee, cm);
            if (c > 0 && t + 1 == rec_t) m_start = mag();
        }
        if (t + 2 <= t_end) {
            float4 ee[4] = {EC0, EC1, EC2, EC3}; float cm = cmC;
            loadC(t + 5);
            step(t + 2, ee, cm);
            if (c > 0 && t + 2 == rec_t) m_start = mag();
        }
    }

    double delta = mag() - m_start;
    if (l < 16) partials[(size_t)(b0 + l) * CHK + c] = (float)delta;
}

// -------- epilogue: out[b] = sum_c partials[b][c] - target[b], fused --------
__global__ __launch_bounds__(256) void epilogue_kernel(
    const float* __restrict__ y_pred, const int* __restrict__ y_true,
    const float* __restrict__ mask, const float* __restrict__ trans,
    const float* __restrict__ partials, float* __restrict__ out)
{
    const int b = blockIdx.x;
    const int tid = threadIdx.x;
    const int*   yt = y_true + (size_t)b * S_;
    const float* mk = mask   + (size_t)b * S_;
    const float* yp = y_pred + (size_t)b * S_ * D_;

    float tacc = 0.f;
    for (int n = tid; n < S_; n += 256) {
        int   tn = yt[n];
        float mn = mk[n];
        tacc += mn * mn * yp[(size_t)n * D_ + tn];
        if (n + 1 < S_) {
            int   tn1 = yt[n + 1];
            float mn1 = mk[n + 1];
            tacc += mn * mn1 * trans[tn * D_ + tn1];
        }
    }
    double v = -(double)tacc;
    if (tid < CHK) v += (double)partials[(size_t)b * CHK + tid];

    #pragma unroll
    for (int m = 32; m >= 1; m >>= 1) v += __shfl_xor(v, m, 64);
    __shared__ double sred[4];
    int wid = tid >> 6;
    if ((tid & 63) == 0) sred[wid] = v;
    __syncthreads();
    if (tid == 0) out[b] = (float)(sred[0] + sred[1] + sred[2] + sred[3]);
}

extern "C" void kernel_launch(void* const* d_in, const int* in_sizes, int n_in,
                              void* d_out, int out_size, void* d_ws, size_t ws_size,
                              hipStream_t stream)
{
    const float* y_pred = (const float*)d_in[0];
    const int*   y_true = (const int*)d_in[1];
    const float* mask   = (const float*)d_in[2];
    const float* trans  = (const float*)d_in[3];
    float* outp     = (float*)d_out;
    float* partials = (float*)((char*)d_ws + 4096);       // 256*128 f

    hipLaunchKernelGGL(mfma_chunk_scan, dim3(16 * CHK), dim3(64), 0, stream,
                       y_pred, mask, trans, partials);
    hipLaunchKernelGGL(epilogue_kernel, dim3(B_), dim3(256), 0, stream,
                       y_pred, y_true, mask, trans, partials, outp);
}

// Round 24
// 52.667 us; speedup vs baseline: 1.0389x; 1.0389x over previous
//
#include <hip/hip_runtime.h>

// CRF loss: out[b] = logZ[b] - target[b].  B=256, S=2048, D=64.
// Round 24: REVERT to r22 (measured best: 52.8us, absmax 0.0).
//   r23's 3-deep prefetch regressed (+1.9us). Four orthogonal levers all
//   measured ~null on this base (occupancy x2, traffic +-20%, chain -30%,
//   MLP +50%) -> structural plateau; this is the keeper kernel.
//   Structure: chunked MFMA scan (CL=16/WUP=4, 2048 waves), exp-at-load,
//   2x2-deep MFMA chains, RNE bf16 packing, wave-uniform pow2 renorm,
//   fused target+combine epilogue.

#define B_   256
#define S_   2048
#define D_   64
#define CHK  128     // chunks per batch
#define CL   16      // accounted steps per chunk
#define WUP  4       // warmup steps

typedef float  f32x4 __attribute__((ext_vector_type(4)));
typedef short  v4s   __attribute__((ext_vector_type(4)));

#if __has_builtin(__builtin_amdgcn_mfma_f32_16x16x16bf16_1k)
static __device__ __forceinline__ f32x4 mfma16(v4s a, v4s b, f32x4 cc) {
    return __builtin_amdgcn_mfma_f32_16x16x16bf16_1k(a, b, cc, 0, 0, 0);
}
#else
static __device__ __forceinline__ f32x4 mfma16(v4s a, v4s b, f32x4 cc) {
    f32x4 d;
    asm("v_mfma_f32_16x16x16_bf16 %0, %1, %2, %3"
        : "=&v"(d) : "v"(a), "v"(b), "v"(cc));
    return d;
}
#endif

// f32 -> bf16 round-to-nearest-even (r15-verified; v_cvt_pk_bf16_f32 truncates)
static __device__ __forceinline__ unsigned bf16_rne(float x) {
    unsigned u = __float_as_uint(x);
    u += 0x7fffu + ((u >> 16) & 1u);
    return u >> 16;
}
static __device__ __forceinline__ float bf2f(short h) {
    return __uint_as_float(((unsigned)(unsigned short)h) << 16);
}
static __device__ __forceinline__ v4s pack4(float a, float b, float c2, float d) {
    union { uint2 u; v4s s; } uu;
    uu.u.x = bf16_rne(a) | (bf16_rne(b) << 16);
    uu.u.y = bf16_rne(c2) | (bf16_rne(d) << 16);
    return uu.s;
}

// ---------------- chunked MFMA forward scan ----------------
// wave u: batch group bg = u&15 (16 batches), chunk c = u>>4.
__global__ __launch_bounds__(64, 2) void mfma_chunk_scan(
    const float* __restrict__ y_pred, const float* __restrict__ mask,
    const float* __restrict__ trans, float* __restrict__ partials)
{
    const int u  = blockIdx.x;
    const int bg = u & 15;
    const int c  = u >> 4;
    const int l  = threadIdx.x;
    const int g  = l >> 4, cb = l & 15;   // g = row quad, cb = batch-in-group
    const int b0 = bg * 16;
    const float* yprowc = y_pred + (size_t)(b0 + cb) * S_ * D_;
    const float* mrowc  = mask   + (size_t)(b0 + cb) * S_;

    // A fragments (r5-verified layout): Av[m][kt] elem e =
    //   exp(trans[16kt+4g+e][16m+cb])
    v4s Av[4][4];
    #pragma unroll
    for (int m = 0; m < 4; ++m)
        #pragma unroll
        for (int kt = 0; kt < 4; ++kt) {
            float a0 = __expf(trans[(16*kt + 4*g + 0) * D_ + 16*m + cb]);
            float a1 = __expf(trans[(16*kt + 4*g + 1) * D_ + 16*m + cb]);
            float a2 = __expf(trans[(16*kt + 4*g + 2) * D_ + 16*m + cb]);
            float a3 = __expf(trans[(16*kt + 4*g + 3) * D_ + 16*m + cb]);
            Av[m][kt] = pack4(a0, a1, a2, a3);
        }

    // state B fragments: Bv[kt] elem e = p[state 16kt+4g+e][batch cb]
    v4s Bv[4];
    if (c == 0) {
        float m0 = mrowc[0];
        #pragma unroll
        for (int kt = 0; kt < 4; ++kt) {
            float p0 = __expf(yprowc[16*kt + 4*g + 0] * m0);
            float p1 = __expf(yprowc[16*kt + 4*g + 1] * m0);
            float p2 = __expf(yprowc[16*kt + 4*g + 2] * m0);
            float p3 = __expf(yprowc[16*kt + 4*g + 3] * m0);
            Bv[kt] = pack4(p0, p1, p2, p3);
        }
    } else {
        const short one = (short)0x3f80;          // bf16(1.0)
        v4s vone = {one, one, one, one};
        #pragma unroll
        for (int kt = 0; kt < 4; ++kt) Bv[kt] = vone;
    }

    int K = 0;                 // wave-uniform exact pow2 offset
    const f32x4 zf = {0.f, 0.f, 0.f, 0.f};

    auto mag = [&]() -> double {
        float s = 0.f;
        #pragma unroll
        for (int m = 0; m < 4; ++m)
            s += (bf2f(Bv[m][0]) + bf2f(Bv[m][1])) +
                 (bf2f(Bv[m][2]) + bf2f(Bv[m][3]));
        s += __shfl_xor(s, 16, 64);
        s += __shfl_xor(s, 32, 64);
        return (double)K * 0.6931471805599453 + (double)__logf(s);
    };

    const int t0    = (c == 0) ? 1 : CL * c - (WUP - 1);
    const int t_end = (CL * (c + 1) > S_ - 1) ? (S_ - 1) : CL * (c + 1);
    const int rec_t = CL * c;          // c>0: record m_start after this step
    double m_start = 0.0;

    // ee = exp(e) values (precomputed at load); cold masked path reloads raw e
    auto step = [&](int t, const float4 (&ee)[4], float cm) {
        // two independent 2-deep MFMA chains per m-tile, merged by one add
        f32x4 accA[4], accB[4];
        #pragma unroll
        for (int m = 0; m < 4; ++m) {
            accA[m] = mfma16(Av[m][0], Bv[0], zf);
            accB[m] = mfma16(Av[m][1], Bv[1], zf);
        }
        #pragma unroll
        for (int m = 0; m < 4; ++m) {
            accA[m] = mfma16(Av[m][2], Bv[2], accA[m]);
            accB[m] = mfma16(Av[m][3], Bv[3], accB[m]);
        }

        f32x4 pr[4];
        if (__builtin_expect(__all(cm == 1.0f), 1)) {
            #pragma unroll
            for (int m = 0; m < 4; ++m) {
                f32x4 acc = accA[m] + accB[m];
                pr[m][0] = acc[0] * ee[m].x;
                pr[m][1] = acc[1] * ee[m].y;
                pr[m][2] = acc[2] * ee[m].z;
                pr[m][3] = acc[3] * ee[m].w;
            }
        } else {
            // cold path: reload raw e (L2-hot), exact masked blend
            const float* ypr = yprowc + (size_t)t * D_ + 4 * g;
            #pragma unroll
            for (int m = 0; m < 4; ++m) {
                f32x4 acc = accA[m] + accB[m];
                #pragma unroll
                for (int e = 0; e < 4; ++e) {
                    float eraw = ypr[16 * m + e];
                    float sum  = acc[e];
                    float pold = bf2f(Bv[m][e]);
                    float pn;
                    if (cm == 1.0f) {
                        pn = sum * __expf(eraw);
                    } else {
                        float outn = __logf(sum) + eraw * cm;
                        float oldl = __logf(pold);
                        pn = __expf(cm * outn + (1.f - cm) * oldl);
                    }
                    pr[m][e] = pn;
                }
            }
        }

        if ((t & 3) == 0) {   // wave-uniform exact pow2 renorm (clamped)
            unsigned rep = __builtin_amdgcn_readfirstlane(__float_as_uint(pr[0][0]));
            int k = (int)((rep >> 23) & 0xffu) - 127;
            k = k < -110 ? -110 : (k > 110 ? 110 : k);
            float sc = __uint_as_float((unsigned)(127 - k) << 23);
            #pragma unroll
            for (int m = 0; m < 4; ++m) {
                pr[m][0] *= sc; pr[m][1] *= sc; pr[m][2] *= sc; pr[m][3] *= sc;
            }
            K += k;
        }

        #pragma unroll
        for (int m = 0; m < 4; ++m)
            Bv[m] = pack4(pr[m][0], pr[m][1], pr[m][2], pr[m][3]);
    };

    // 2-deep ping-pong prefetch; exp applied at load (off the step chain)
    float4 EA0, EA1, EA2, EA3, EB0, EB1, EB2, EB3;
    float  cmA, cmB;
    auto expf4 = [](float4 v) {
        float4 r; r.x = __expf(v.x); r.y = __expf(v.y);
        r.z = __expf(v.z); r.w = __expf(v.w); return r;
    };
    auto loadA = [&](int t) {
        int tt = t > t_end ? t_end : t;
        const float* base = yprowc + (size_t)tt * D_ + 4 * g;
        EA0 = expf4(*(const float4*)(base +  0));
        EA1 = expf4(*(const float4*)(base + 16));
        EA2 = expf4(*(const float4*)(base + 32));
        EA3 = expf4(*(const float4*)(base + 48));
        cmA = mrowc[tt];
    };
    auto loadB = [&](int t) {
        int tt = t > t_end ? t_end : t;
        const float* base = yprowc + (size_t)tt * D_ + 4 * g;
        EB0 = expf4(*(const float4*)(base +  0));
        EB1 = expf4(*(const float4*)(base + 16));
        EB2 = expf4(*(const float4*)(base + 32));
        EB3 = expf4(*(const float4*)(base + 48));
        cmB = mrowc[tt];
    };

    loadA(t0); loadB(t0 + 1);
    for (int t = t0; t <= t_end; t += 2) {
        {
            float4 ee[4] = {EA0, EA1, EA2, EA3}; float cm = cmA;
            loadA(t + 2);
            step(t, ee, cm);
            if (c > 0 && t == rec_t) m_start = mag();
        }
        if (t + 1 <= t_end) {
            float4 ee[4] = {EB0, EB1, EB2, EB3}; float cm = cmB;
            loadB(t + 3);
            step(t + 1, ee, cm);
            if (c > 0 && t + 1 == rec_t) m_start = mag();
        }
    }

    double delta = mag() - m_start;
    if (l < 16) partials[(size_t)(b0 + l) * CHK + c] = (float)delta;
}

// -------- epilogue: out[b] = sum_c partials[b][c] - target[b], fused --------
__global__ __launch_bounds__(256) void epilogue_kernel(
    const float* __restrict__ y_pred, const int* __restrict__ y_true,
    const float* __restrict__ mask, const float* __restrict__ trans,
    const float* __restrict__ partials, float* __restrict__ out)
{
    const int b = blockIdx.x;
    const int tid = threadIdx.x;
    const int*   yt = y_true + (size_t)b * S_;
    const float* mk = mask   + (size_t)b * S_;
    const float* yp = y_pred + (size_t)b * S_ * D_;

    float tacc = 0.f;
    for (int n = tid; n < S_; n += 256) {
        int   tn = yt[n];
        float mn = mk[n];
        tacc += mn * mn * yp[(size_t)n * D_ + tn];
        if (n + 1 < S_) {
            int   tn1 = yt[n + 1];
            float mn1 = mk[n + 1];
            tacc += mn * mn1 * trans[tn * D_ + tn1];
        }
    }
    double v = -(double)tacc;
    if (tid < CHK) v += (double)partials[(size_t)b * CHK + tid];

    #pragma unroll
    for (int m = 32; m >= 1; m >>= 1) v += __shfl_xor(v, m, 64);
    __shared__ double sred[4];
    int wid = tid >> 6;
    if ((tid & 63) == 0) sred[wid] = v;
    __syncthreads();
    if (tid == 0) out[b] = (float)(sred[0] + sred[1] + sred[2] + sred[3]);
}

extern "C" void kernel_launch(void* const* d_in, const int* in_sizes, int n_in,
                              void* d_out, int out_size, void* d_ws, size_t ws_size,
                              hipStream_t stream)
{
    const float* y_pred = (const float*)d_in[0];
    const int*   y_true = (const int*)d_in[1];
    const float* mask   = (const float*)d_in[2];
    const float* trans  = (const float*)d_in[3];
    float* outp     = (float*)d_out;
    float* partials = (float*)((char*)d_ws + 4096);       // 256*128 f

    hipLaunchKernelGGL(mfma_chunk_scan, dim3(16 * CHK), dim3(64), 0, stream,
                       y_pred, mask, trans, partials);
    hipLaunchKernelGGL(epilogue_kernel, dim3(B_), dim3(256), 0, stream,
                       y_pred, y_true, mask, trans, partials, outp);
}